// Round 1
// baseline (5022.844 us; speedup 1.0000x reference)
//
#include <hip/hip_runtime.h>

#define NENT 40943

typedef short bf16x8 __attribute__((ext_vector_type(8)));
typedef float f32x4 __attribute__((ext_vector_type(4)));

__device__ __forceinline__ unsigned short f2bf(float f) {
  unsigned int u = __builtin_bit_cast(unsigned int, f);
  u += 0x7fffu + ((u >> 16) & 1u);   // RNE
  return (unsigned short)(u >> 16);
}
__device__ __forceinline__ float bf2f(unsigned short h) {
  unsigned int u = ((unsigned int)h) << 16;
  return __builtin_bit_cast(float, u);
}

// K2 = 2000*log2(e): logK/ln2 = A2[s] + B2[s]*mm[m] + C2[m]
#define K2C 2885.3900817779268f

// ---------------------------------------------------------------- init
// flags layout: per plan p, 12 block-flags, each on its own 64B line (16 u32),
// two phase-parity slots (u32 each) at word offsets 0 and 1.
__global__ void init_k(const float* __restrict__ emb_ent, const float* __restrict__ img,
                       const float* __restrict__ ling, float* __restrict__ phi,
                       float* __restrict__ gam, float* __restrict__ A2, float* __restrict__ B2,
                       float* __restrict__ C2, unsigned int* __restrict__ flags) {
  const int p = blockIdx.x, t = threadIdx.x;
  const int pm = p % 10;
  const bool isImg = (p < 10);
  const int D = isImg ? 1000 : 768;
  const float* st = emb_ent + (size_t)pm * 512;
  const float* mm = isImg ? (img + (size_t)pm * 1000) : (ling + (size_t)pm * 768);
  for (int s = t; s < 512; s += 256) {
    float sv = st[s];
    A2[p * 512 + s] = -K2C * sv * sv;
    B2[p * 512 + s] = 2.f * K2C * sv;
    gam[p * 512 + s] = 0.f;
  }
  for (int m = t; m < 1024; m += 256) {
    float c2 = 0.f;
    if (m < D) { float mv = mm[m]; c2 = -K2C * mv * mv; }
    C2[p * 1024 + m] = c2;
    phi[p * 1024 + m] = 0.f;
  }
  if (t < 24) flags[p * 192 + (t >> 1) * 16 + (t & 1)] = 0u;
}

// ---------------------------------------------------------------- sinkhorn
// 20 plans x 12 blocks. log2-domain potentials: phi = log2e*20*f, gam = log2e*20*g.
// Grid sync: per-block flag words (separate cachelines), store-release +
// relaxed polls; value = (phase<<1) | changedBit, slot = phase&1.
// Early exit when one full f+g iteration is bit-identical for every block
// (then all later iterations repeat exactly -> identical to 100 iters).
__global__ __launch_bounds__(256) void sinkhorn_k(
    const float* __restrict__ img, const float* __restrict__ ling,
    float* __restrict__ phi, float* __restrict__ gam,
    const float* __restrict__ A2, const float* __restrict__ B2,
    const float* __restrict__ C2, unsigned int* __restrict__ flags) {
  const int bid = blockIdx.x;
  const int p = bid / 12, j = bid % 12;
  const int pm = p % 10;
  const bool isImg = (p < 10);
  const int D = isImg ? 1000 : 768;
  const float* mm = isImg ? (img + (size_t)pm * 1000) : (ling + (size_t)pm * 768);
  float* phiP = phi + p * 1024;
  float* gamP = gam + p * 512;
  const float* A2P = A2 + p * 512;
  const float* B2P = B2 + p * 512;
  const float* C2P = C2 + p * 1024;
  unsigned int* flagP = flags + p * 192;
  const float negLog2D = isImg ? -9.965784284662087f : -9.584962500721156f;

  const int TPMF = isImg ? 3 : 4;          // threads per m in f-step
  const int fChunk = isImg ? 84 : 64;
  const int fm0 = j * fChunk;
  int fCount = D - fm0; if (fCount > fChunk) fCount = fChunk;
  const int gs0 = j * 43;
  int gCount = 512 - gs0; if (gCount > 43) gCount = 43;

  __shared__ float2 wb[512];    // (A2+gam, B2)
  __shared__ float2 um[1024];   // (C2+phi, mm)
  __shared__ float redM[256];
  __shared__ float redA[256];
  __shared__ int sChg;          // this block's chunk changed this phase
  __shared__ int sAnyF;         // any block's f chunk changed this iteration
  __shared__ int sAnyG;         // any block's g chunk changed this iteration

  const int t = threadIdx.x;
  for (int s = t; s < 512; s += 256) wb[s].y = B2P[s];
  for (int m = t; m < D; m += 256) um[m].y = mm[m];
  if (t == 0) sChg = 0;

  const int fml = t / TPMF, fq = t - fml * TPMF;
  const bool fAct = (fml < fCount);
  const int fs0 = (fq * 512) / TPMF, fs1 = ((fq + 1) * 512) / TPMF;
  const int fmG = fm0 + fml;
  float fmm = 0.f, fC2 = 0.f;
  if (fAct) { fmm = mm[fmG]; fC2 = C2P[fmG]; }

  const int gsl = t / 5, gq = t - gsl * 5;
  const bool gAct = (gsl < gCount);
  const int gm0 = (gq * D) / 5, gm1 = ((gq + 1) * D) / 5;
  const int gsG = gs0 + gsl;
  float gA2 = 0.f;
  if (gAct) gA2 = A2P[gsG];

  unsigned int phase = 0;

  for (int it = 0; it < 100; ++it) {
    // ---- f-step: f over m, LSE over s ----
    for (int s = t; s < 512; s += 256) wb[s].x = A2P[s] + gamP[s];
    __syncthreads();
    if (fAct) {
      float vmax = -3.0e38f;
      for (int s = fs0; s < fs1; ++s) {
        float2 w = wb[s];
        vmax = fmaxf(vmax, fmaf(w.y, fmm, w.x));
      }
      float acc = 0.f;
      for (int s = fs0; s < fs1; ++s) {
        float2 w = wb[s];
        acc += __builtin_exp2f(fmaf(w.y, fmm, w.x) - vmax);
      }
      redM[t] = vmax; redA[t] = acc;
    }
    __syncthreads();
    if (fAct && fq == 0) {
      float vmax = redM[t], acc = redA[t];
      for (int q = 1; q < TPMF; ++q) {
        float m2 = redM[t + q], a2 = redA[t + q];
        float M = fmaxf(vmax, m2);
        acc = acc * __builtin_exp2f(vmax - M) + a2 * __builtin_exp2f(m2 - M);
        vmax = M;
      }
      float nv = negLog2D - fC2 - vmax - __builtin_log2f(acc);
      if (nv != phiP[fmG]) sChg = 1;   // benign race, all writers store 1
      phiP[fmG] = nv;
    }
    phase++;
    __syncthreads();                   // phi writes + sChg final
    if (t == 0) {
      __threadfence();                 // release: phi visible before flag
      __hip_atomic_store(flagP + j * 16 + (phase & 1u),
                         (phase << 1) | (unsigned)sChg,
                         __ATOMIC_RELAXED, __HIP_MEMORY_SCOPE_AGENT);
    }
    {
      int any = 0;
      if (t < 12) {
        unsigned int v;
        for (;;) {
          v = __hip_atomic_load(flagP + t * 16 + (phase & 1u),
                                __ATOMIC_RELAXED, __HIP_MEMORY_SCOPE_AGENT);
          if ((v >> 1) >= phase) break;
          __builtin_amdgcn_s_sleep(1);
        }
        any = (int)(v & 1u);
      }
      if (t < 64) {
        unsigned long long ball = __ballot(any);
        if (t == 0) sAnyF = (ball != 0ull);
      }
    }
    __syncthreads();                   // all polls complete, sAnyF published
    if (t == 0) { __threadfence(); sChg = 0; }  // acquire: invalidate L1
    __syncthreads();

    // ---- g-step: g over s, LSE over m ----
    for (int m = t; m < D; m += 256) um[m].x = C2P[m] + phiP[m];
    __syncthreads();
    if (gAct) {
      float bs = wb[gsG].y;
      float vmax = -3.0e38f;
      for (int m = gm0; m < gm1; ++m) {
        float2 u = um[m];
        vmax = fmaxf(vmax, fmaf(u.y, bs, u.x));
      }
      float acc = 0.f;
      for (int m = gm0; m < gm1; ++m) {
        float2 u = um[m];
        acc += __builtin_exp2f(fmaf(u.y, bs, u.x) - vmax);
      }
      redM[t] = vmax; redA[t] = acc;
    }
    __syncthreads();
    if (gAct && gq == 0) {
      float vmax = redM[t], acc = redA[t];
      for (int q = 1; q < 5; ++q) {
        float m2 = redM[t + q], a2 = redA[t + q];
        float M = fmaxf(vmax, m2);
        acc = acc * __builtin_exp2f(vmax - M) + a2 * __builtin_exp2f(m2 - M);
        vmax = M;
      }
      float nv = -9.0f - gA2 - vmax - __builtin_log2f(acc);
      if (nv != gamP[gsG]) sChg = 1;
      gamP[gsG] = nv;
    }
    phase++;
    __syncthreads();
    if (t == 0) {
      __threadfence();
      __hip_atomic_store(flagP + j * 16 + (phase & 1u),
                         (phase << 1) | (unsigned)sChg,
                         __ATOMIC_RELAXED, __HIP_MEMORY_SCOPE_AGENT);
    }
    {
      int any = 0;
      if (t < 12) {
        unsigned int v;
        for (;;) {
          v = __hip_atomic_load(flagP + t * 16 + (phase & 1u),
                                __ATOMIC_RELAXED, __HIP_MEMORY_SCOPE_AGENT);
          if ((v >> 1) >= phase) break;
          __builtin_amdgcn_s_sleep(1);
        }
        any = (int)(v & 1u);
      }
      if (t < 64) {
        unsigned long long ball = __ballot(any);
        if (t == 0) sAnyG = (ball != 0ull);
      }
    }
    __syncthreads();
    if (t == 0) { __threadfence(); sChg = 0; }
    __syncthreads();
    if (!sAnyF && !sAnyG) break;       // exact fixed point -> identical to 100 iters
  }
}

// ---------------------------------------------------------------- build B^T (scaled), bf16 [512][1792]
__global__ void build_b(const float* __restrict__ mats_img, const float* __restrict__ mats_ling,
                        const float* __restrict__ img, const float* __restrict__ ling,
                        const float* __restrict__ phi, const float* __restrict__ gam,
                        const float* __restrict__ A2, const float* __restrict__ B2,
                        const float* __restrict__ C2, unsigned short* __restrict__ BbigT) {
  const int k = blockIdx.x, t = threadIdx.x;
  if (k >= 1768) {
    for (int n = t; n < 512; n += 256) BbigT[(size_t)n * 1792 + k] = 0;
    return;
  }
  const bool isImg = (k < 1000);
  const int kk = isImg ? k : (k - 1000);
  __shared__ float sU[10], sMM[10];
  if (t < 10) {
    const int p = isImg ? t : (10 + t);
    sU[t] = C2[p * 1024 + kk] + phi[p * 1024 + kk];
    sMM[t] = isImg ? img[(size_t)t * 1000 + kk] : ling[(size_t)t * 768 + kk];
  }
  __syncthreads();
  const float* mats = isImg ? mats_img : mats_ling;
  const float scale = isImg ? 0.1f : 0.8f;
  const int pbase = isImg ? 0 : 10;
  for (int n = t; n < 512; n += 256) {
    float val = 0.f;
    #pragma unroll
    for (int i = 0; i < 10; ++i) {
      const int p = pbase + i;
      float a = A2[p * 512 + n] + gam[p * 512 + n];
      float b = B2[p * 512 + n];
      val += __builtin_exp2f(fmaf(b, sMM[i], a + sU[i]));
    }
    float outv = scale * fmaf(5120.f, val, mats[(size_t)kk * 512 + n]);
    BbigT[(size_t)n * 1792 + k] = f2bf(outv);
  }
}

// ---------------------------------------------------------------- gemm1: embedding (bf16) [40943][512]
// XCD swizzle: group the 4 n-tiles of each m-tile onto one XCD so the A-panel
// (f32 img/ling rows) is fetched into that XCD's L2 once and reused 4x.
__global__ __launch_bounds__(256) void gemm1_k(
    const float* __restrict__ img, const float* __restrict__ ling,
    const float* __restrict__ emb_ent, const unsigned short* __restrict__ BbigT,
    unsigned short* __restrict__ Eb) {
  const int bid0 = blockIdx.x;
  const int wg = (bid0 & 7) * 160 + (bid0 >> 3);   // 1280 = 8 * 160, bijective
  const int nt = wg & 3, mt = wg >> 2;
  const int m0 = mt * 128, n0 = nt * 128;
  __shared__ __align__(16) unsigned short As[128 * 40];
  __shared__ __align__(16) unsigned short Bs[128 * 40];
  const int t = threadIdx.x;
  const int wave = t >> 6, lane = t & 63;
  const int quad = lane >> 4, lrow = lane & 15;
  const int wm = (wave & 1) * 64, wn = (wave >> 1) * 64;
  f32x4 acc[4][4];
  #pragma unroll
  for (int a = 0; a < 4; ++a)
    #pragma unroll
    for (int b = 0; b < 4; ++b) acc[a][b] = (f32x4){0.f, 0.f, 0.f, 0.f};

  const int r = t >> 1, h = t & 1;
  const int gm = m0 + r;
  const bool mOK = (gm < NENT);
  const float* arowI = img + (size_t)gm * 1000;
  const float* arowL = ling + (size_t)gm * 768;
  const unsigned short* brow = BbigT + (size_t)(n0 + r) * 1792;
  unsigned short* asDst = As + r * 40 + h * 16;
  unsigned short* bsDst = Bs + r * 40 + h * 16;

  for (int k0 = 0; k0 < 1792; k0 += 32) {
    const int ck = k0 + h * 16;
    unsigned short u[16];
    #pragma unroll
    for (int q4 = 0; q4 < 4; ++q4) {
      const int kk = ck + q4 * 4;
      f32x4 v = (f32x4){0.f, 0.f, 0.f, 0.f};
      if (mOK) {
        if (kk < 1000) v = *(const f32x4*)(arowI + kk);
        else if (kk < 1768) v = *(const f32x4*)(arowL + (kk - 1000));
      }
      u[q4 * 4 + 0] = f2bf(v.x); u[q4 * 4 + 1] = f2bf(v.y);
      u[q4 * 4 + 2] = f2bf(v.z); u[q4 * 4 + 3] = f2bf(v.w);
    }
    bf16x8 w0, w1;
    #pragma unroll
    for (int i2 = 0; i2 < 8; ++i2) { w0[i2] = (short)u[i2]; w1[i2] = (short)u[8 + i2]; }
    *(bf16x8*)asDst = w0;
    *(bf16x8*)(asDst + 8) = w1;
    bf16x8 b0 = *(const bf16x8*)(brow + ck);
    bf16x8 b1 = *(const bf16x8*)(brow + ck + 8);
    *(bf16x8*)bsDst = b0;
    *(bf16x8*)(bsDst + 8) = b1;
    __syncthreads();
    bf16x8 af[4], bfv[4];
    #pragma unroll
    for (int i2 = 0; i2 < 4; ++i2) {
      af[i2] = *(const bf16x8*)(As + (wm + i2 * 16 + lrow) * 40 + quad * 8);
      bfv[i2] = *(const bf16x8*)(Bs + (wn + i2 * 16 + lrow) * 40 + quad * 8);
    }
    #pragma unroll
    for (int mi = 0; mi < 4; ++mi)
      #pragma unroll
      for (int ni = 0; ni < 4; ++ni)
        acc[mi][ni] = __builtin_amdgcn_mfma_f32_16x16x32_bf16(af[mi], bfv[ni], acc[mi][ni], 0, 0, 0);
    __syncthreads();
  }
  #pragma unroll
  for (int mi = 0; mi < 4; ++mi) {
    const int mbase = m0 + wm + mi * 16 + quad * 4;
    #pragma unroll
    for (int ni = 0; ni < 4; ++ni) {
      const int n = n0 + wn + ni * 16 + lrow;
      #pragma unroll
      for (int rr = 0; rr < 4; ++rr) {
        const int gm2 = mbase + rr;
        if (gm2 < NENT) {
          float v = acc[mi][ni][rr] + 0.1f * emb_ent[(size_t)gm2 * 512 + n];
          Eb[(size_t)gm2 * 512 + n] = f2bf(v);
        }
      }
    }
  }
}

// ---------------------------------------------------------------- gather + c-build + factors
__global__ void gather_c(const int* __restrict__ x, const unsigned short* __restrict__ Eb,
                         const float* __restrict__ emb_rel, unsigned short* __restrict__ cb,
                         float* __restrict__ outF) {
  const int i = blockIdx.x, t = threadIdx.x;
  if (i >= 1000) {
    cb[(size_t)i * 512 + t] = 0;
    cb[(size_t)i * 512 + 256 + t] = 0;
    return;
  }
  const int hI = x[i * 3 + 0], rI = x[i * 3 + 1], tI = x[i * 3 + 2];
  const float l0 = bf2f(Eb[(size_t)hI * 512 + t]);
  const float l1 = bf2f(Eb[(size_t)hI * 512 + 256 + t]);
  const float r0 = emb_rel[(size_t)rI * 512 + t];
  const float r1 = emb_rel[(size_t)rI * 512 + 256 + t];
  const float h0 = bf2f(Eb[(size_t)tI * 512 + t]);
  const float h1 = bf2f(Eb[(size_t)tI * 512 + 256 + t]);
  cb[(size_t)i * 512 + t] = f2bf(l0 * r0 - l1 * r1);
  cb[(size_t)i * 512 + 256 + t] = f2bf(l0 * r1 + l1 * r0);
  outF[(size_t)i * 256 + t] = sqrtf(l0 * l0 + l1 * l1);
  outF[256000 + (size_t)i * 256 + t] = sqrtf(r0 * r0 + r1 * r1);
  outF[512000 + (size_t)i * 256 + t] = sqrtf(h0 * h0 + h1 * h1);
}

// ---------------------------------------------------------------- gemm2: scores [1000][40943]
// XCD swizzle: group the 8 m-tiles of each n-tile onto one XCD so the Eb
// n-panel is fetched into that XCD's L2 once and reused 8x.
__global__ __launch_bounds__(256) void gemm2_k(
    const unsigned short* __restrict__ cb, const unsigned short* __restrict__ Eb,
    float* __restrict__ scores) {
  const int bid0 = blockIdx.x;
  const int wg = (bid0 & 7) * 320 + (bid0 >> 3);   // 2560 = 8 * 320, bijective
  const int mt = wg & 7, nt = wg >> 3;
  const int m0 = mt * 128, n0 = nt * 128;
  __shared__ __align__(16) unsigned short As[128 * 40];
  __shared__ __align__(16) unsigned short Bs[128 * 40];
  const int t = threadIdx.x;
  const int wave = t >> 6, lane = t & 63;
  const int quad = lane >> 4, lrow = lane & 15;
  const int wm = (wave & 1) * 64, wn = (wave >> 1) * 64;
  f32x4 acc[4][4];
  #pragma unroll
  for (int a = 0; a < 4; ++a)
    #pragma unroll
    for (int b = 0; b < 4; ++b) acc[a][b] = (f32x4){0.f, 0.f, 0.f, 0.f};

  const int r = t >> 1, h = t & 1;
  const unsigned short* arow = cb + (size_t)(m0 + r) * 512;
  const int ge = n0 + r;
  const bool nOK = (ge < NENT);
  const unsigned short* browE = Eb + (size_t)ge * 512;
  unsigned short* asDst = As + r * 40 + h * 16;
  unsigned short* bsDst = Bs + r * 40 + h * 16;

  for (int k0 = 0; k0 < 512; k0 += 32) {
    const int ck = k0 + h * 16;
    bf16x8 a0 = *(const bf16x8*)(arow + ck);
    bf16x8 a1 = *(const bf16x8*)(arow + ck + 8);
    *(bf16x8*)asDst = a0;
    *(bf16x8*)(asDst + 8) = a1;
    bf16x8 b0 = (bf16x8)0, b1 = (bf16x8)0;
    if (nOK) { b0 = *(const bf16x8*)(browE + ck); b1 = *(const bf16x8*)(browE + ck + 8); }
    *(bf16x8*)bsDst = b0;
    *(bf16x8*)(bsDst + 8) = b1;
    __syncthreads();
    bf16x8 af[4], bfv[4];
    #pragma unroll
    for (int i2 = 0; i2 < 4; ++i2) {
      af[i2] = *(const bf16x8*)(As + (wm + i2 * 16 + lrow) * 40 + quad * 8);
      bfv[i2] = *(const bf16x8*)(Bs + (wn + i2 * 16 + lrow) * 40 + quad * 8);
    }
    #pragma unroll
    for (int mi = 0; mi < 4; ++mi)
      #pragma unroll
      for (int ni = 0; ni < 4; ++ni)
        acc[mi][ni] = __builtin_amdgcn_mfma_f32_16x16x32_bf16(af[mi], bfv[ni], acc[mi][ni], 0, 0, 0);
    __syncthreads();
  }
  #pragma unroll
  for (int mi = 0; mi < 4; ++mi) {
    const int mbase = m0 + wm + mi * 16 + quad * 4;
    #pragma unroll
    for (int ni = 0; ni < 4; ++ni) {
      const int n = n0 + wn + ni * 16 + lrow;
      if (n < NENT) {
        #pragma unroll
        for (int rr = 0; rr < 4; ++rr) {
          const int i = mbase + rr;
          if (i < 1000) scores[(size_t)i * NENT + n] = acc[mi][ni][rr];
        }
      }
    }
  }
}

// ---------------------------------------------------------------- launch
extern "C" void kernel_launch(void* const* d_in, const int* in_sizes, int n_in,
                              void* d_out, int out_size, void* d_ws, size_t ws_size,
                              hipStream_t stream) {
  (void)in_sizes; (void)n_in; (void)out_size; (void)ws_size;
  const int*   x        = (const int*)d_in[0];
  const float* emb_ent  = (const float*)d_in[1];
  const float* emb_rel  = (const float*)d_in[2];
  const float* mats_img = (const float*)d_in[3];
  const float* mats_ling= (const float*)d_in[4];
  const float* img_vec  = (const float*)d_in[5];
  const float* ling_vec = (const float*)d_in[6];
  float* out = (float*)d_out;

  // workspace layout (all 16B-aligned by construction)
  float* phi = (float*)d_ws;                       // 20*1024
  float* gam = phi + 20 * 1024;                    // 20*512
  float* A2  = gam + 20 * 512;                     // 20*512
  float* B2  = A2 + 20 * 512;                      // 20*512
  float* C2  = B2 + 20 * 512;                      // 20*1024
  unsigned int* flags = (unsigned int*)(C2 + 20 * 1024);       // 20*192 (12 flags * 16 u32)
  unsigned short* BbigT = (unsigned short*)(flags + 20 * 192); // 512*1792 bf16
  unsigned short* Eb = BbigT + (size_t)512 * 1792;             // 40943*512 bf16
  unsigned short* cb = Eb + (size_t)NENT * 512;                // 1024*512 bf16

  init_k<<<dim3(20), dim3(256), 0, stream>>>(emb_ent, img_vec, ling_vec, phi, gam, A2, B2, C2, flags);
  sinkhorn_k<<<dim3(240), dim3(256), 0, stream>>>(img_vec, ling_vec, phi, gam, A2, B2, C2, flags);
  build_b<<<dim3(1792), dim3(256), 0, stream>>>(mats_img, mats_ling, img_vec, ling_vec,
                                                phi, gam, A2, B2, C2, BbigT);
  gemm1_k<<<dim3(1280), dim3(256), 0, stream>>>(img_vec, ling_vec, emb_ent, BbigT, Eb);
  gather_c<<<dim3(1024), dim3(256), 0, stream>>>(x, Eb, emb_rel, cb, out + (size_t)1000 * NENT);
  gemm2_k<<<dim3(2560), dim3(256), 0, stream>>>(cb, Eb, out);
}

// Round 2
// 3162.621 us; speedup vs baseline: 1.5882x; 1.5882x over previous
//
#include <hip/hip_runtime.h>

#define NENT 40943

typedef short bf16x8 __attribute__((ext_vector_type(8)));
typedef float f32x4 __attribute__((ext_vector_type(4)));

__device__ __forceinline__ unsigned short f2bf(float f) {
  unsigned int u = __builtin_bit_cast(unsigned int, f);
  u += 0x7fffu + ((u >> 16) & 1u);   // RNE
  return (unsigned short)(u >> 16);
}
__device__ __forceinline__ float bf2f(unsigned short h) {
  unsigned int u = ((unsigned int)h) << 16;
  return __builtin_bit_cast(float, u);
}

// K2 = 2000*log2(e): logK/ln2 = A2[s] + B2[s]*mm[m] + C2[m]
#define K2C 2885.3900817779268f

__device__ __forceinline__ float aload(const float* p) {
  return __hip_atomic_load(p, __ATOMIC_RELAXED, __HIP_MEMORY_SCOPE_AGENT);
}
__device__ __forceinline__ void astore(float* p, float v) {
  __hip_atomic_store(p, v, __ATOMIC_RELAXED, __HIP_MEMORY_SCOPE_AGENT);
}

// ---------------------------------------------------------------- init
// flags: per plan p, 12 block phase-counters, each on its own 64B line.
__global__ void init_k(const float* __restrict__ emb_ent, const float* __restrict__ img,
                       const float* __restrict__ ling, float* __restrict__ phi,
                       float* __restrict__ gam, float* __restrict__ A2, float* __restrict__ B2,
                       float* __restrict__ C2, unsigned int* __restrict__ flags) {
  const int p = blockIdx.x, t = threadIdx.x;
  const int pm = p % 10;
  const bool isImg = (p < 10);
  const int D = isImg ? 1000 : 768;
  const float* st = emb_ent + (size_t)pm * 512;
  const float* mm = isImg ? (img + (size_t)pm * 1000) : (ling + (size_t)pm * 768);
  for (int s = t; s < 512; s += 256) {
    float sv = st[s];
    A2[p * 512 + s] = -K2C * sv * sv;
    B2[p * 512 + s] = 2.f * K2C * sv;
    gam[p * 512 + s] = 0.f;
  }
  for (int m = t; m < 1024; m += 256) {
    float c2 = 0.f;
    if (m < D) { float mv = mm[m]; c2 = -K2C * mv * mv; }
    C2[p * 1024 + m] = c2;
    phi[p * 1024 + m] = 0.f;
  }
  if (t < 12) flags[p * 192 + t * 16] = 0u;
}

// ---------------------------------------------------------------- sinkhorn
// 20 plans x 12 blocks x 512 threads. log2-domain: phi = log2e*20*f, gam = log2e*20*g.
// Fence-free cross-block sync: ALL cross-block data (phi/gam) moves via
// agent-scope relaxed atomics (sc1 -> coherent point, no L2 maintenance).
// __syncthreads() drains each wave's vmcnt before s_barrier, so after the
// barrier every store in the block has completed at the coherent point;
// then one monotone phase-counter store per block + 12 parallel polls.
__global__ __launch_bounds__(512) void sinkhorn_k(
    const float* __restrict__ img, const float* __restrict__ ling,
    float* __restrict__ phi, float* __restrict__ gam,
    const float* __restrict__ A2, const float* __restrict__ B2,
    const float* __restrict__ C2, unsigned int* __restrict__ flags) {
  const int bid = blockIdx.x;
  const int p = bid / 12, j = bid % 12;
  const int pm = p % 10;
  const bool isImg = (p < 10);
  const int D = isImg ? 1000 : 768;
  const float* mm = isImg ? (img + (size_t)pm * 1000) : (ling + (size_t)pm * 768);
  float* phiP = phi + p * 1024;
  float* gamP = gam + p * 512;
  const float* A2P = A2 + p * 512;
  const float* B2P = B2 + p * 512;
  const float* C2P = C2 + p * 1024;
  unsigned int* flagP = flags + p * 192;
  const float negLog2D = isImg ? -9.965784284662087f : -9.584962500721156f;

  const int TPMF = isImg ? 6 : 8;          // threads per m in f-step (512 thr)
  const int fChunk = isImg ? 84 : 64;
  const int fm0 = j * fChunk;
  int fCount = D - fm0; if (fCount > fChunk) fCount = fChunk;
  const int gs0 = j * 43;
  int gCount = 512 - gs0; if (gCount > 43) gCount = 43;

  __shared__ float2 wb[512];    // (A2+gam, B2)
  __shared__ float2 um[1024];   // (C2+phi, mm)
  __shared__ float redM[512];
  __shared__ float redA[512];

  const int t = threadIdx.x;
  if (t < 512) wb[t].y = B2P[t];
  for (int m = t; m < D; m += 512) um[m].y = mm[m];

  const int fml = t / TPMF, fq = t - fml * TPMF;
  const bool fAct = (fml < fCount);
  const int fs0 = (fq * 512) / TPMF, fs1 = ((fq + 1) * 512) / TPMF;
  const int fmG = fm0 + fml;
  float fmm = 0.f, fC2 = 0.f;
  if (fAct) { fmm = mm[fmG]; fC2 = C2P[fmG]; }

  const int TPMG = 11;
  const int gsl = t / TPMG, gq = t - gsl * TPMG;
  const bool gAct = (gsl < gCount);
  const int gm0 = (gq * D) / TPMG, gm1 = ((gq + 1) * D) / TPMG;
  const int gsG = gs0 + gsl;
  float gA2 = 0.f;
  if (gAct) gA2 = A2P[gsG];

  unsigned int phase = 0;

  for (int it = 0; it < 100; ++it) {
    // ---- f-step: f over m, LSE over s ----
    if (t < 512) wb[t].x = A2P[t] + aload(&gamP[t]);
    __syncthreads();
    if (fAct) {
      float vmax = -3.0e38f;
      for (int s = fs0; s < fs1; ++s) {
        float2 w = wb[s];
        vmax = fmaxf(vmax, fmaf(w.y, fmm, w.x));
      }
      float acc = 0.f;
      for (int s = fs0; s < fs1; ++s) {
        float2 w = wb[s];
        acc += __builtin_exp2f(fmaf(w.y, fmm, w.x) - vmax);
      }
      redM[t] = vmax; redA[t] = acc;
    }
    __syncthreads();
    if (fAct && fq == 0) {
      float vmax = redM[t], acc = redA[t];
      for (int q = 1; q < TPMF; ++q) {
        float m2 = redM[t + q], a2 = redA[t + q];
        float M = fmaxf(vmax, m2);
        acc = acc * __builtin_exp2f(vmax - M) + a2 * __builtin_exp2f(m2 - M);
        vmax = M;
      }
      astore(&phiP[fmG], negLog2D - fC2 - vmax - __builtin_log2f(acc));
    }
    phase++;
    __syncthreads();                       // drains every wave's stores (vmcnt 0)
    if (t == 0)
      __hip_atomic_store(flagP + j * 16, phase, __ATOMIC_RELAXED, __HIP_MEMORY_SCOPE_AGENT);
    if (t < 12) {
      while (__hip_atomic_load(flagP + t * 16, __ATOMIC_RELAXED, __HIP_MEMORY_SCOPE_AGENT) < phase)
        __builtin_amdgcn_s_sleep(1);
    }
    __syncthreads();

    // ---- g-step: g over s, LSE over m ----
    for (int m = t; m < D; m += 512) um[m].x = C2P[m] + aload(&phiP[m]);
    __syncthreads();
    if (gAct) {
      float bs = wb[gsG].y;
      float vmax = -3.0e38f;
      for (int m = gm0; m < gm1; ++m) {
        float2 u = um[m];
        vmax = fmaxf(vmax, fmaf(u.y, bs, u.x));
      }
      float acc = 0.f;
      for (int m = gm0; m < gm1; ++m) {
        float2 u = um[m];
        acc += __builtin_exp2f(fmaf(u.y, bs, u.x) - vmax);
      }
      redM[t] = vmax; redA[t] = acc;
    }
    __syncthreads();
    if (gAct && gq == 0) {
      float vmax = redM[t], acc = redA[t];
      for (int q = 1; q < TPMG; ++q) {
        float m2 = redM[t + q], a2 = redA[t + q];
        float M = fmaxf(vmax, m2);
        acc = acc * __builtin_exp2f(vmax - M) + a2 * __builtin_exp2f(m2 - M);
        vmax = M;
      }
      astore(&gamP[gsG], -9.0f - gA2 - vmax - __builtin_log2f(acc));
    }
    phase++;
    __syncthreads();
    if (t == 0)
      __hip_atomic_store(flagP + j * 16, phase, __ATOMIC_RELAXED, __HIP_MEMORY_SCOPE_AGENT);
    if (t < 12) {
      while (__hip_atomic_load(flagP + t * 16, __ATOMIC_RELAXED, __HIP_MEMORY_SCOPE_AGENT) < phase)
        __builtin_amdgcn_s_sleep(1);
    }
    __syncthreads();
  }
}

// ---------------------------------------------------------------- build B^T (scaled), bf16 [512][1792]
__global__ void build_b(const float* __restrict__ mats_img, const float* __restrict__ mats_ling,
                        const float* __restrict__ img, const float* __restrict__ ling,
                        const float* __restrict__ phi, const float* __restrict__ gam,
                        const float* __restrict__ A2, const float* __restrict__ B2,
                        const float* __restrict__ C2, unsigned short* __restrict__ BbigT) {
  const int k = blockIdx.x, t = threadIdx.x;
  if (k >= 1768) {
    for (int n = t; n < 512; n += 256) BbigT[(size_t)n * 1792 + k] = 0;
    return;
  }
  const bool isImg = (k < 1000);
  const int kk = isImg ? k : (k - 1000);
  __shared__ float sU[10], sMM[10];
  if (t < 10) {
    const int p = isImg ? t : (10 + t);
    sU[t] = C2[p * 1024 + kk] + phi[p * 1024 + kk];
    sMM[t] = isImg ? img[(size_t)t * 1000 + kk] : ling[(size_t)t * 768 + kk];
  }
  __syncthreads();
  const float* mats = isImg ? mats_img : mats_ling;
  const float scale = isImg ? 0.1f : 0.8f;
  const int pbase = isImg ? 0 : 10;
  for (int n = t; n < 512; n += 256) {
    float val = 0.f;
    #pragma unroll
    for (int i = 0; i < 10; ++i) {
      const int p = pbase + i;
      float a = A2[p * 512 + n] + gam[p * 512 + n];
      float b = B2[p * 512 + n];
      val += __builtin_exp2f(fmaf(b, sMM[i], a + sU[i]));
    }
    float outv = scale * fmaf(5120.f, val, mats[(size_t)kk * 512 + n]);
    BbigT[(size_t)n * 1792 + k] = f2bf(outv);
  }
}

// ---------------------------------------------------------------- gemm1: embedding (bf16) [40943][512]
// XCD swizzle: group the 4 n-tiles of each m-tile onto one XCD so the A-panel
// (f32 img/ling rows) is fetched into that XCD's L2 once and reused 4x.
__global__ __launch_bounds__(256) void gemm1_k(
    const float* __restrict__ img, const float* __restrict__ ling,
    const float* __restrict__ emb_ent, const unsigned short* __restrict__ BbigT,
    unsigned short* __restrict__ Eb) {
  const int bid0 = blockIdx.x;
  const int wg = (bid0 & 7) * 160 + (bid0 >> 3);   // 1280 = 8 * 160, bijective
  const int nt = wg & 3, mt = wg >> 2;
  const int m0 = mt * 128, n0 = nt * 128;
  __shared__ __align__(16) unsigned short As[128 * 40];
  __shared__ __align__(16) unsigned short Bs[128 * 40];
  const int t = threadIdx.x;
  const int wave = t >> 6, lane = t & 63;
  const int quad = lane >> 4, lrow = lane & 15;
  const int wm = (wave & 1) * 64, wn = (wave >> 1) * 64;
  f32x4 acc[4][4];
  #pragma unroll
  for (int a = 0; a < 4; ++a)
    #pragma unroll
    for (int b = 0; b < 4; ++b) acc[a][b] = (f32x4){0.f, 0.f, 0.f, 0.f};

  const int r = t >> 1, h = t & 1;
  const int gm = m0 + r;
  const bool mOK = (gm < NENT);
  const float* arowI = img + (size_t)gm * 1000;
  const float* arowL = ling + (size_t)gm * 768;
  const unsigned short* brow = BbigT + (size_t)(n0 + r) * 1792;
  unsigned short* asDst = As + r * 40 + h * 16;
  unsigned short* bsDst = Bs + r * 40 + h * 16;

  for (int k0 = 0; k0 < 1792; k0 += 32) {
    const int ck = k0 + h * 16;
    unsigned short u[16];
    #pragma unroll
    for (int q4 = 0; q4 < 4; ++q4) {
      const int kk = ck + q4 * 4;
      f32x4 v = (f32x4){0.f, 0.f, 0.f, 0.f};
      if (mOK) {
        if (kk < 1000) v = *(const f32x4*)(arowI + kk);
        else if (kk < 1768) v = *(const f32x4*)(arowL + (kk - 1000));
      }
      u[q4 * 4 + 0] = f2bf(v.x); u[q4 * 4 + 1] = f2bf(v.y);
      u[q4 * 4 + 2] = f2bf(v.z); u[q4 * 4 + 3] = f2bf(v.w);
    }
    bf16x8 w0, w1;
    #pragma unroll
    for (int i2 = 0; i2 < 8; ++i2) { w0[i2] = (short)u[i2]; w1[i2] = (short)u[8 + i2]; }
    *(bf16x8*)asDst = w0;
    *(bf16x8*)(asDst + 8) = w1;
    bf16x8 b0 = *(const bf16x8*)(brow + ck);
    bf16x8 b1 = *(const bf16x8*)(brow + ck + 8);
    *(bf16x8*)bsDst = b0;
    *(bf16x8*)(bsDst + 8) = b1;
    __syncthreads();
    bf16x8 af[4], bfv[4];
    #pragma unroll
    for (int i2 = 0; i2 < 4; ++i2) {
      af[i2] = *(const bf16x8*)(As + (wm + i2 * 16 + lrow) * 40 + quad * 8);
      bfv[i2] = *(const bf16x8*)(Bs + (wn + i2 * 16 + lrow) * 40 + quad * 8);
    }
    #pragma unroll
    for (int mi = 0; mi < 4; ++mi)
      #pragma unroll
      for (int ni = 0; ni < 4; ++ni)
        acc[mi][ni] = __builtin_amdgcn_mfma_f32_16x16x32_bf16(af[mi], bfv[ni], acc[mi][ni], 0, 0, 0);
    __syncthreads();
  }
  #pragma unroll
  for (int mi = 0; mi < 4; ++mi) {
    const int mbase = m0 + wm + mi * 16 + quad * 4;
    #pragma unroll
    for (int ni = 0; ni < 4; ++ni) {
      const int n = n0 + wn + ni * 16 + lrow;
      #pragma unroll
      for (int rr = 0; rr < 4; ++rr) {
        const int gm2 = mbase + rr;
        if (gm2 < NENT) {
          float v = acc[mi][ni][rr] + 0.1f * emb_ent[(size_t)gm2 * 512 + n];
          Eb[(size_t)gm2 * 512 + n] = f2bf(v);
        }
      }
    }
  }
}

// ---------------------------------------------------------------- gather + c-build + factors
__global__ void gather_c(const int* __restrict__ x, const unsigned short* __restrict__ Eb,
                         const float* __restrict__ emb_rel, unsigned short* __restrict__ cb,
                         float* __restrict__ outF) {
  const int i = blockIdx.x, t = threadIdx.x;
  if (i >= 1000) {
    cb[(size_t)i * 512 + t] = 0;
    cb[(size_t)i * 512 + 256 + t] = 0;
    return;
  }
  const int hI = x[i * 3 + 0], rI = x[i * 3 + 1], tI = x[i * 3 + 2];
  const float l0 = bf2f(Eb[(size_t)hI * 512 + t]);
  const float l1 = bf2f(Eb[(size_t)hI * 512 + 256 + t]);
  const float r0 = emb_rel[(size_t)rI * 512 + t];
  const float r1 = emb_rel[(size_t)rI * 512 + 256 + t];
  const float h0 = bf2f(Eb[(size_t)tI * 512 + t]);
  const float h1 = bf2f(Eb[(size_t)tI * 512 + 256 + t]);
  cb[(size_t)i * 512 + t] = f2bf(l0 * r0 - l1 * r1);
  cb[(size_t)i * 512 + 256 + t] = f2bf(l0 * r1 + l1 * r0);
  outF[(size_t)i * 256 + t] = sqrtf(l0 * l0 + l1 * l1);
  outF[256000 + (size_t)i * 256 + t] = sqrtf(r0 * r0 + r1 * r1);
  outF[512000 + (size_t)i * 256 + t] = sqrtf(h0 * h0 + h1 * h1);
}

// ---------------------------------------------------------------- gemm2: scores [1000][40943]
// XCD swizzle: group the 8 m-tiles of each n-tile onto one XCD so the Eb
// n-panel is fetched into that XCD's L2 once and reused 8x.
__global__ __launch_bounds__(256) void gemm2_k(
    const unsigned short* __restrict__ cb, const unsigned short* __restrict__ Eb,
    float* __restrict__ scores) {
  const int bid0 = blockIdx.x;
  const int wg = (bid0 & 7) * 320 + (bid0 >> 3);   // 2560 = 8 * 320, bijective
  const int mt = wg & 7, nt = wg >> 3;
  const int m0 = mt * 128, n0 = nt * 128;
  __shared__ __align__(16) unsigned short As[128 * 40];
  __shared__ __align__(16) unsigned short Bs[128 * 40];
  const int t = threadIdx.x;
  const int wave = t >> 6, lane = t & 63;
  const int quad = lane >> 4, lrow = lane & 15;
  const int wm = (wave & 1) * 64, wn = (wave >> 1) * 64;
  f32x4 acc[4][4];
  #pragma unroll
  for (int a = 0; a < 4; ++a)
    #pragma unroll
    for (int b = 0; b < 4; ++b) acc[a][b] = (f32x4){0.f, 0.f, 0.f, 0.f};

  const int r = t >> 1, h = t & 1;
  const unsigned short* arow = cb + (size_t)(m0 + r) * 512;
  const int ge = n0 + r;
  const bool nOK = (ge < NENT);
  const unsigned short* browE = Eb + (size_t)ge * 512;
  unsigned short* asDst = As + r * 40 + h * 16;
  unsigned short* bsDst = Bs + r * 40 + h * 16;

  for (int k0 = 0; k0 < 512; k0 += 32) {
    const int ck = k0 + h * 16;
    bf16x8 a0 = *(const bf16x8*)(arow + ck);
    bf16x8 a1 = *(const bf16x8*)(arow + ck + 8);
    *(bf16x8*)asDst = a0;
    *(bf16x8*)(asDst + 8) = a1;
    bf16x8 b0 = (bf16x8)0, b1 = (bf16x8)0;
    if (nOK) { b0 = *(const bf16x8*)(browE + ck); b1 = *(const bf16x8*)(browE + ck + 8); }
    *(bf16x8*)bsDst = b0;
    *(bf16x8*)(bsDst + 8) = b1;
    __syncthreads();
    bf16x8 af[4], bfv[4];
    #pragma unroll
    for (int i2 = 0; i2 < 4; ++i2) {
      af[i2] = *(const bf16x8*)(As + (wm + i2 * 16 + lrow) * 40 + quad * 8);
      bfv[i2] = *(const bf16x8*)(Bs + (wn + i2 * 16 + lrow) * 40 + quad * 8);
    }
    #pragma unroll
    for (int mi = 0; mi < 4; ++mi)
      #pragma unroll
      for (int ni = 0; ni < 4; ++ni)
        acc[mi][ni] = __builtin_amdgcn_mfma_f32_16x16x32_bf16(af[mi], bfv[ni], acc[mi][ni], 0, 0, 0);
    __syncthreads();
  }
  #pragma unroll
  for (int mi = 0; mi < 4; ++mi) {
    const int mbase = m0 + wm + mi * 16 + quad * 4;
    #pragma unroll
    for (int ni = 0; ni < 4; ++ni) {
      const int n = n0 + wn + ni * 16 + lrow;
      if (n < NENT) {
        #pragma unroll
        for (int rr = 0; rr < 4; ++rr) {
          const int i = mbase + rr;
          if (i < 1000) scores[(size_t)i * NENT + n] = acc[mi][ni][rr];
        }
      }
    }
  }
}

// ---------------------------------------------------------------- launch
extern "C" void kernel_launch(void* const* d_in, const int* in_sizes, int n_in,
                              void* d_out, int out_size, void* d_ws, size_t ws_size,
                              hipStream_t stream) {
  (void)in_sizes; (void)n_in; (void)out_size; (void)ws_size;
  const int*   x        = (const int*)d_in[0];
  const float* emb_ent  = (const float*)d_in[1];
  const float* emb_rel  = (const float*)d_in[2];
  const float* mats_img = (const float*)d_in[3];
  const float* mats_ling= (const float*)d_in[4];
  const float* img_vec  = (const float*)d_in[5];
  const float* ling_vec = (const float*)d_in[6];
  float* out = (float*)d_out;

  // workspace layout (all 16B-aligned by construction)
  float* phi = (float*)d_ws;                       // 20*1024
  float* gam = phi + 20 * 1024;                    // 20*512
  float* A2  = gam + 20 * 512;                     // 20*512
  float* B2  = A2 + 20 * 512;                      // 20*512
  float* C2  = B2 + 20 * 512;                      // 20*1024
  unsigned int* flags = (unsigned int*)(C2 + 20 * 1024);       // 20*192 (12 counters * 16 u32)
  unsigned short* BbigT = (unsigned short*)(flags + 20 * 192); // 512*1792 bf16
  unsigned short* Eb = BbigT + (size_t)512 * 1792;             // 40943*512 bf16
  unsigned short* cb = Eb + (size_t)NENT * 512;                // 1024*512 bf16

  init_k<<<dim3(20), dim3(256), 0, stream>>>(emb_ent, img_vec, ling_vec, phi, gam, A2, B2, C2, flags);
  sinkhorn_k<<<dim3(240), dim3(512), 0, stream>>>(img_vec, ling_vec, phi, gam, A2, B2, C2, flags);
  build_b<<<dim3(1792), dim3(256), 0, stream>>>(mats_img, mats_ling, img_vec, ling_vec,
                                                phi, gam, A2, B2, C2, BbigT);
  gemm1_k<<<dim3(1280), dim3(256), 0, stream>>>(img_vec, ling_vec, emb_ent, BbigT, Eb);
  gather_c<<<dim3(1024), dim3(256), 0, stream>>>(x, Eb, emb_rel, cb, out + (size_t)1000 * NENT);
  gemm2_k<<<dim3(2560), dim3(256), 0, stream>>>(cb, Eb, out);
}